// Round 9
// baseline (1530.959 us; speedup 1.0000x reference)
//
#include <hip/hip_runtime.h>

#define NPERM_C 250000
#define P_C     4000000          // slots = NPERM * 16
#define G_C     4096
#define NB1     1954             // ceil(P_C / 2048) big scan
#define NB2     123              // ceil(NPERM_C / 2048) pool scan

typedef __attribute__((ext_vector_type(8))) short bf16x8;
typedef __attribute__((ext_vector_type(4))) float f32x4;

static __device__ __forceinline__ unsigned short f2bf(float f) {
    unsigned u = __float_as_uint(f);
    unsigned r = (u + 0x7fffu + ((u >> 16) & 1u)) >> 16;   // RNE
    return (unsigned short)r;
}
static __device__ __forceinline__ float bf2f(unsigned short s) {
    return __uint_as_float(((unsigned)s) << 16);
}
static __device__ __forceinline__ unsigned long long pack4(ushort4 s) {
    return (unsigned long long)s.x | ((unsigned long long)s.y << 16) |
           ((unsigned long long)s.z << 32) | ((unsigned long long)s.w << 48);
}

// ---------------------------------------------------------------------------
// fragment-ordered split-bf16 weight tables
// ---------------------------------------------------------------------------
__global__ void repack_bpk(const float* __restrict__ w, unsigned short* __restrict__ bpk) {
    int o = blockIdx.x * 256 + threadIdx.x;          // 131072 total
    int j = o & 7, lane = (o >> 3) & 63, h = (o >> 9) & 1;
    int nt = (o >> 10) & 3, ks = (o >> 12) & 1, l = o >> 13;
    int b = ks * 32 + (lane >> 4) * 8 + j;
    int c = nt * 16 + (lane & 15);
    float wv = w[(b * 64 + c) * 16 + l];
    unsigned short hb = f2bf(wv);
    bpk[o] = (h == 0) ? hb : f2bf(wv - bf2f(hb));
}

__global__ void repack_wlpk(const float* __restrict__ wl, unsigned short* __restrict__ wpk) {
    int o = blockIdx.x * 256 + threadIdx.x;          // 8192 total
    int j = o & 7, lane = (o >> 3) & 63, h = (o >> 9) & 1;
    int nt = (o >> 10) & 3, ks = o >> 12;
    int k = ks * 32 + (lane >> 4) * 8 + j;
    int c2 = nt * 16 + (lane & 15);
    float wv = wl[c2 * 64 + k];
    unsigned short hb = f2bf(wv);
    wpk[o] = (h == 0) ? hb : f2bf(wv - bf2f(hb));
}

// ---------------------------------------------------------------------------
// pool reference histogram: poolCnt[c] = #times perm row c is pooled.
// ---------------------------------------------------------------------------
__global__ __launch_bounds__(256) void pool_hist(const int* __restrict__ pcol,
                                                 int* __restrict__ poolCnt) {
    int i = blockIdx.x * 256 + threadIdx.x;
    if (i < NPERM_C) atomicAdd(&poolCnt[pcol[i]], 1);
}

// active-row compaction scan (flag = cnt!=0), deterministic.
__global__ __launch_bounds__(256) void pool_scan_local(const int* __restrict__ poolCnt,
                                                       int* __restrict__ poolRk,
                                                       int* __restrict__ bsum2) {
    __shared__ int ts[256];
    int b = blockIdx.x, t = threadIdx.x;
    int base = b * 2048 + t * 8;
    int v[8]; int s = 0;
#pragma unroll
    for (int i = 0; i < 8; ++i) {
        int idx = base + i;
        v[i] = (idx < NPERM_C) ? (poolCnt[idx] != 0) : 0;
        s += v[i];
    }
    ts[t] = s;
    __syncthreads();
    for (int ofs = 1; ofs < 256; ofs <<= 1) {
        int xv = (t >= ofs) ? ts[t - ofs] : 0;
        __syncthreads();
        ts[t] += xv;
        __syncthreads();
    }
    int run = ts[t] - s;
    if (t == 255) bsum2[b] = ts[255];
#pragma unroll
    for (int i = 0; i < 8; ++i) {
        int idx = base + i;
        if (idx < NPERM_C) poolRk[idx] = run;
        run += v[i];
    }
}

__global__ void pool_scan_top(int* __restrict__ bsum2) {
    __shared__ int ts[256];
    int t = threadIdx.x;
    int v = (t < NB2) ? bsum2[t] : 0;
    ts[t] = v;
    __syncthreads();
    for (int ofs = 1; ofs < 256; ofs <<= 1) {
        int xv = (t >= ofs) ? ts[t - ofs] : 0;
        __syncthreads();
        ts[t] += xv;
        __syncthreads();
    }
    if (t < NB2) bsum2[t] = ts[t] - v;
}

// finalize: poolRk[idx] := ((rank)<<1) | activeFlag ; nActB[0] = #active
__global__ __launch_bounds__(256) void pool_scan_add(const int* __restrict__ poolCnt,
                                                     int* __restrict__ poolRk,
                                                     const int* __restrict__ bsum2,
                                                     int* __restrict__ nActB) {
    int b = blockIdx.x, t = threadIdx.x;
    int add = bsum2[b];
    int base = b * 2048 + t * 8;
#pragma unroll
    for (int i = 0; i < 8; ++i) {
        int idx = base + i;
        if (idx < NPERM_C) {
            int flag = poolCnt[idx] != 0;
            int o = poolRk[idx] + add;
            poolRk[idx] = (o << 1) | flag;
            if (idx == NPERM_C - 1) nActB[0] = o + flag;
        }
    }
}

// ---------------------------------------------------------------------------
// slot histogram over ACTIVE rows, compact slot space, 8 entries/thread.
// ---------------------------------------------------------------------------
__global__ __launch_bounds__(256) void hist(const int* __restrict__ r1,
                                            const int* __restrict__ r2,
                                            const int* __restrict__ poolRk,
                                            int* __restrict__ cnt) {
    int i8 = (blockIdx.x * 256 + threadIdx.x) * 8;
    if (i8 >= 2 * P_C) return;
    const int* src = (i8 < P_C) ? (r1 + i8) : (r2 + (i8 - P_C));
    int4 ra = *reinterpret_cast<const int4*>(src);
    int4 rb = *reinterpret_cast<const int4*>(src + 4);
    int rr[8] = {ra.x, ra.y, ra.z, ra.w, rb.x, rb.y, rb.z, rb.w};
#pragma unroll
    for (int q = 0; q < 8; ++q) {
        int info = poolRk[rr[q] >> 4];
        if (info & 1) atomicAdd(&cnt[(info >> 1) * 16 + (rr[q] & 15)], 1);
    }
}

// big exclusive scan over 4M slot counts.
__global__ __launch_bounds__(256) void scan_local(const int* __restrict__ cnt,
                                                  int* __restrict__ off,
                                                  int* __restrict__ bsum) {
    __shared__ int ts[256];
    int b = blockIdx.x, t = threadIdx.x;
    int base = b * 2048 + t * 8;
    int v[8]; int s = 0;
#pragma unroll
    for (int i = 0; i < 8; ++i) {
        int idx = base + i;
        v[i] = (idx < P_C) ? cnt[idx] : 0;
        s += v[i];
    }
    ts[t] = s;
    __syncthreads();
    for (int ofs = 1; ofs < 256; ofs <<= 1) {
        int xv = (t >= ofs) ? ts[t - ofs] : 0;
        __syncthreads();
        ts[t] += xv;
        __syncthreads();
    }
    int run = ts[t] - s;
    if (t == 255) bsum[b] = ts[255];
#pragma unroll
    for (int i = 0; i < 8; ++i) {
        int idx = base + i;
        if (idx < P_C) off[idx] = run;
        run += v[i];
    }
}

__global__ void scan_top(int* __restrict__ bsum) {
    __shared__ int ts[256];
    int t = threadIdx.x;
    int base = t * 8;
    int v[8]; int s = 0;
#pragma unroll
    for (int i = 0; i < 8; ++i) {
        int idx = base + i;
        v[i] = (idx < NB1) ? bsum[idx] : 0;
        s += v[i];
    }
    ts[t] = s;
    __syncthreads();
    for (int ofs = 1; ofs < 256; ofs <<= 1) {
        int xv = (t >= ofs) ? ts[t - ofs] : 0;
        __syncthreads();
        ts[t] += xv;
        __syncthreads();
    }
    int run = ts[t] - s;
#pragma unroll
    for (int i = 0; i < 8; ++i) {
        int idx = base + i;
        if (idx < NB1) bsum[idx] = run;
        run += v[i];
    }
}

__global__ __launch_bounds__(256) void scan_add(int* __restrict__ off,
                                                const int* __restrict__ bsum,
                                                int* __restrict__ cur) {
    int b = blockIdx.x, t = threadIdx.x;
    int add = bsum[b];
    int base = b * 2048 + t * 8;
#pragma unroll
    for (int i = 0; i < 8; ++i) {
        int idx = base + i;
        if (idx < P_C) {
            int o = off[idx] + add;
            if (idx == P_C - 1) off[P_C] = o + cur[idx];  // cur still holds count
            off[idx] = o;
            cur[idx] = o;
        }
    }
}

// ---------------------------------------------------------------------------
// scatter active entries to sorted position, 4 entries/thread, nt stores.
// ---------------------------------------------------------------------------
__global__ __launch_bounds__(256) void scat(
        const int* __restrict__ r1, const int* __restrict__ c1, const float* __restrict__ v1,
        const int* __restrict__ r2, const int* __restrict__ c2, const float* __restrict__ v2,
        const int* __restrict__ poolRk,
        int* __restrict__ cur, unsigned long long* __restrict__ suv) {
    int i4 = (blockIdx.x * 256 + threadIdx.x) * 4;
    if (i4 >= 2 * P_C) return;
    const int* rr; const int* cc; const float* vv; unsigned srcbit; int base;
    if (i4 < P_C) { rr = r1; cc = c1; vv = v1; srcbit = 0u; base = i4; }
    else          { rr = r2; cc = c2; vv = v2; srcbit = 0x100000u; base = i4 - P_C; }
    int4 r = *reinterpret_cast<const int4*>(rr + base);
    int4 c = *reinterpret_cast<const int4*>(cc + base);
    float4 v = *reinterpret_cast<const float4*>(vv + base);
    int rs[4] = {r.x, r.y, r.z, r.w};
    int cs[4] = {c.x, c.y, c.z, c.w};
    float vs[4] = {v.x, v.y, v.z, v.w};
#pragma unroll
    for (int q = 0; q < 4; ++q) {
        int info = poolRk[rs[q] >> 4];
        if (info & 1) {
            int pos = atomicAdd(&cur[(info >> 1) * 16 + (rs[q] & 15)], 1);
            unsigned long long e = (unsigned long long)((unsigned)cs[q] | srcbit) |
                                   ((unsigned long long)__float_as_uint(vs[q]) << 32);
            __builtin_nontemporal_store(e, suv + pos);
        }
    }
}

// ---------------------------------------------------------------------------
// CSR gather: block = 4 compact rows, 16 groups of 16 lanes; each group owns
// the 4 consecutive-slot chains of one (row, slot-quad): boundaries come from
// one int4 + one scalar pOff load; 4 independent load chains interleaved.
// The degree-gate slot 5*q4 is sub-chain q4 of quad q4. nt loads for suv,
// nt stores for the split-bf16 planes (write-once).
// ---------------------------------------------------------------------------
__global__ __launch_bounds__(256) void gather_nfeat(
        const unsigned long long* __restrict__ suv, const int* __restrict__ pOff,
        const float* __restrict__ x, const float* __restrict__ efeat,
        const float* __restrict__ degs, const int* __restrict__ nActB,
        unsigned short* __restrict__ nfH, unsigned short* __restrict__ nfL,
        float* __restrict__ degD, int row0, int rows) {
    int nAct = nActB[0];
    int t = threadIdx.x;
    int gid = t >> 4;            // 0..15  (wave = gid>>2 = row)
    int t16 = t & 15;
    int r4 = gid >> 2;           // row within block (wave-uniform)
    int q4 = gid & 3;            // slot quad
    int cr = row0 + blockIdx.x * 4 + r4;
    int rend = row0 + rows; if (rend > nAct) rend = nAct;
    if (cr >= rend) return;      // wave-uniform exit
    int sBase = cr * 16 + q4 * 4;
    int4 bo = *reinterpret_cast<const int4*>(pOff + sBase);
    int e4 = pOff[sBase + 4];
    int i0 = bo.x, e0 = bo.y;
    int i1 = bo.y, e1 = bo.z;
    int i2 = bo.z, e2 = bo.w;
    int i3 = bo.w, e3 = e4;
    float4 a0 = {0,0,0,0}, a1 = {0,0,0,0}, a2 = {0,0,0,0}, a3 = {0,0,0,0};
    float dq = 0.f;              // degree accum for sub-chain q4
    while ((i0 < e0) | (i1 < e1) | (i2 < e2) | (i3 < e3)) {
        bool h0 = i0 < e0, h1 = i1 < e1, h2 = i2 < e2, h3 = i3 < e3;
        unsigned long long k0, k1, k2, k3;
        if (h0) k0 = __builtin_nontemporal_load(suv + i0);
        if (h1) k1 = __builtin_nontemporal_load(suv + i1);
        if (h2) k2 = __builtin_nontemporal_load(suv + i2);
        if (h3) k3 = __builtin_nontemporal_load(suv + i3);
        if (h0) {
            unsigned k = (unsigned)k0; float v = __uint_as_float((unsigned)(k0 >> 32));
            const float* f = (k & 0x100000u) ? efeat : x;
            float4 fv = *reinterpret_cast<const float4*>(
                f + (size_t)(k & 0xFFFFFu) * 64 + t16 * 4);
            a0.x = fmaf(v, fv.x, a0.x); a0.y = fmaf(v, fv.y, a0.y);
            a0.z = fmaf(v, fv.z, a0.z); a0.w = fmaf(v, fv.w, a0.w);
            if (q4 == 0 && !(k & 0x100000u)) dq = fmaf(v, degs[k & 0xFFFFFu], dq);
            ++i0;
        }
        if (h1) {
            unsigned k = (unsigned)k1; float v = __uint_as_float((unsigned)(k1 >> 32));
            const float* f = (k & 0x100000u) ? efeat : x;
            float4 fv = *reinterpret_cast<const float4*>(
                f + (size_t)(k & 0xFFFFFu) * 64 + t16 * 4);
            a1.x = fmaf(v, fv.x, a1.x); a1.y = fmaf(v, fv.y, a1.y);
            a1.z = fmaf(v, fv.z, a1.z); a1.w = fmaf(v, fv.w, a1.w);
            if (q4 == 1 && !(k & 0x100000u)) dq = fmaf(v, degs[k & 0xFFFFFu], dq);
            ++i1;
        }
        if (h2) {
            unsigned k = (unsigned)k2; float v = __uint_as_float((unsigned)(k2 >> 32));
            const float* f = (k & 0x100000u) ? efeat : x;
            float4 fv = *reinterpret_cast<const float4*>(
                f + (size_t)(k & 0xFFFFFu) * 64 + t16 * 4);
            a2.x = fmaf(v, fv.x, a2.x); a2.y = fmaf(v, fv.y, a2.y);
            a2.z = fmaf(v, fv.z, a2.z); a2.w = fmaf(v, fv.w, a2.w);
            if (q4 == 2 && !(k & 0x100000u)) dq = fmaf(v, degs[k & 0xFFFFFu], dq);
            ++i2;
        }
        if (h3) {
            unsigned k = (unsigned)k3; float v = __uint_as_float((unsigned)(k3 >> 32));
            const float* f = (k & 0x100000u) ? efeat : x;
            float4 fv = *reinterpret_cast<const float4*>(
                f + (size_t)(k & 0xFFFFFu) * 64 + t16 * 4);
            a3.x = fmaf(v, fv.x, a3.x); a3.y = fmaf(v, fv.y, a3.y);
            a3.z = fmaf(v, fv.z, a3.z); a3.w = fmaf(v, fv.w, a3.w);
            if (q4 == 3 && !(k & 0x100000u)) dq = fmaf(v, degs[k & 0xFFFFFu], dq);
            ++i3;
        }
    }
    size_t o = ((size_t)(cr - row0) * 16 + q4 * 4) * 64 + t16 * 4;
    float4 as[4] = {a0, a1, a2, a3};
#pragma unroll
    for (int c = 0; c < 4; ++c) {
        ushort4 h4, l4;
        h4.x = f2bf(as[c].x); l4.x = f2bf(as[c].x - bf2f(h4.x));
        h4.y = f2bf(as[c].y); l4.y = f2bf(as[c].y - bf2f(h4.y));
        h4.z = f2bf(as[c].z); l4.z = f2bf(as[c].z - bf2f(h4.z));
        h4.w = f2bf(as[c].w); l4.w = f2bf(as[c].w - bf2f(h4.w));
        __builtin_nontemporal_store(pack4(h4),
            reinterpret_cast<unsigned long long*>(nfH + o + (size_t)c * 64));
        __builtin_nontemporal_store(pack4(l4),
            reinterpret_cast<unsigned long long*>(nfL + o + (size_t)c * 64));
    }
    if (t16 == 0) degD[(size_t)cr * 4 + q4] = dq;
}

// ---------------------------------------------------------------------------
// degree-gate MLP over compact rows [r0, min(r0+rows, nAct)).
// ---------------------------------------------------------------------------
__global__ __launch_bounds__(256) void dg_gemm(
        const float* __restrict__ degD,
        const float* __restrict__ W0, const float* __restrict__ b0,
        const float* __restrict__ W1, const float* __restrict__ b1,
        const int* __restrict__ nActB,
        float* __restrict__ dgb, int r0, int rows) {
    __shared__ float hidT[128][68];   // [h][r]
    __shared__ float w1T[128][68];    // [h][c]
    __shared__ float dloc[64][4];
    __shared__ float w0s[128][5];
    int nAct = nActB[0];
    int rend = r0 + rows; if (rend > nAct) rend = nAct;
    int t = threadIdx.x;
    int m0 = r0 + blockIdx.x * 64;
    if (m0 >= rend) return;

    {
        int r = t >> 2, j = t & 3;
        int gr = m0 + r; if (gr >= rend) gr = rend - 1;
        dloc[r][j] = degD[(size_t)gr * 4 + j];
    }
    if (t < 128) {
        w0s[t][0] = W0[t * 4 + 0]; w0s[t][1] = W0[t * 4 + 1];
        w0s[t][2] = W0[t * 4 + 2]; w0s[t][3] = W0[t * 4 + 3];
        w0s[t][4] = b0[t];
    }
    for (int s = 0; s < 32; ++s) {
        int idx = t + s * 256;
        w1T[idx & 127][idx >> 7] = W1[idx];
    }
    __syncthreads();
    for (int s = 0; s < 32; ++s) {
        int idx = t + s * 256;
        int h = idx & 127, r = idx >> 7;
        float v = w0s[h][4] + dloc[r][0] * w0s[h][0] + dloc[r][1] * w0s[h][1]
                            + dloc[r][2] * w0s[h][2] + dloc[r][3] * w0s[h][3];
        hidT[h][r] = fmaxf(v, 0.f);
    }
    __syncthreads();

    int tm = t >> 4, tn = t & 15;
    float acc[4][4] = {};
#pragma unroll 8
    for (int k = 0; k < 128; ++k) {
        float4 a = *reinterpret_cast<const float4*>(&hidT[k][tm * 4]);
        float4 b = *reinterpret_cast<const float4*>(&w1T[k][tn * 4]);
        acc[0][0] = fmaf(a.x, b.x, acc[0][0]); acc[0][1] = fmaf(a.x, b.y, acc[0][1]);
        acc[0][2] = fmaf(a.x, b.z, acc[0][2]); acc[0][3] = fmaf(a.x, b.w, acc[0][3]);
        acc[1][0] = fmaf(a.y, b.x, acc[1][0]); acc[1][1] = fmaf(a.y, b.y, acc[1][1]);
        acc[1][2] = fmaf(a.y, b.z, acc[1][2]); acc[1][3] = fmaf(a.y, b.w, acc[1][3]);
        acc[2][0] = fmaf(a.z, b.x, acc[2][0]); acc[2][1] = fmaf(a.z, b.y, acc[2][1]);
        acc[2][2] = fmaf(a.z, b.z, acc[2][2]); acc[2][3] = fmaf(a.z, b.w, acc[2][3]);
        acc[3][0] = fmaf(a.w, b.x, acc[3][0]); acc[3][1] = fmaf(a.w, b.y, acc[3][1]);
        acc[3][2] = fmaf(a.w, b.z, acc[3][2]); acc[3][3] = fmaf(a.w, b.w, acc[3][3]);
    }
    float bb[4] = {b1[tn * 4 + 0], b1[tn * 4 + 1], b1[tn * 4 + 2], b1[tn * 4 + 3]};
#pragma unroll
    for (int i = 0; i < 4; ++i) {
        int grow = m0 + tm * 4 + i;
        if (grow < rend) {
            float4 o = {acc[i][0] + bb[0], acc[i][1] + bb[1],
                        acc[i][2] + bb[2], acc[i][3] + bb[3]};
            *reinterpret_cast<float4*>(&dgb[(size_t)grow * 64 + tn * 4]) = o;
        }
    }
}

// ---------------------------------------------------------------------------
// MFMA einsum + epilogue (split-bf16, 3 products) over compact rows.
// ---------------------------------------------------------------------------
__global__ __launch_bounds__(256) void gemm_mfma(
        const unsigned short* __restrict__ nfH, const unsigned short* __restrict__ nfL,
        const unsigned short* __restrict__ Bpk, const unsigned short* __restrict__ Wlpk,
        const float* __restrict__ bias, const float* __restrict__ bl,
        const float* __restrict__ dgb, const int* __restrict__ nActB,
        float* __restrict__ outb, int r0, int rows) {
    __shared__ unsigned short Hh[128][72];
    __shared__ unsigned short Hl[128][72];
    int nAct = nActB[0];
    int rowsEff = rows; if (r0 + rowsEff > nAct) rowsEff = nAct - r0;
    int t = threadIdx.x, lane = t & 63, w = t >> 6;
    int m0 = blockIdx.x * 128;
    if (m0 >= rowsEff) return;
    int r16 = lane & 15, kg = lane >> 4;

    f32x4 acc[2][4];
#pragma unroll
    for (int i = 0; i < 2; ++i)
#pragma unroll
        for (int j = 0; j < 4; ++j) acc[i][j] = (f32x4){0.f, 0.f, 0.f, 0.f};

    for (int l = 0; l < 16; ++l) {
#pragma unroll
        for (int ks = 0; ks < 2; ++ks) {
            bf16x8 ah[2], al[2];
#pragma unroll
            for (int mt = 0; mt < 2; ++mt) {
                int lr = m0 + w * 32 + mt * 16 + r16;
                if (lr >= rowsEff) lr = rowsEff - 1;
                size_t off = ((size_t)lr * 16 + l) * 64 + ks * 32 + kg * 8;
                ah[mt] = *reinterpret_cast<const bf16x8*>(nfH + off);
                al[mt] = *reinterpret_cast<const bf16x8*>(nfL + off);
            }
#pragma unroll
            for (int nt = 0; nt < 4; ++nt) {
                const unsigned short* bb =
                    Bpk + (size_t)(((l * 2 + ks) * 4 + nt) * 2) * 512 + lane * 8;
                bf16x8 bh = *reinterpret_cast<const bf16x8*>(bb);
                bf16x8 blo = *reinterpret_cast<const bf16x8*>(bb + 512);
#pragma unroll
                for (int mt = 0; mt < 2; ++mt) {
                    acc[mt][nt] = __builtin_amdgcn_mfma_f32_16x16x32_bf16(ah[mt], bh,  acc[mt][nt], 0, 0, 0);
                    acc[mt][nt] = __builtin_amdgcn_mfma_f32_16x16x32_bf16(ah[mt], blo, acc[mt][nt], 0, 0, 0);
                    acc[mt][nt] = __builtin_amdgcn_mfma_f32_16x16x32_bf16(al[mt], bh,  acc[mt][nt], 0, 0, 0);
                }
            }
        }
    }

    // epilogue 1: h = relu(acc + bias) -> split-bf16 LDS planes
#pragma unroll
    for (int mt = 0; mt < 2; ++mt)
#pragma unroll
        for (int nt = 0; nt < 4; ++nt) {
            int col = nt * 16 + r16;
            float bv = bias[col];
#pragma unroll
            for (int reg = 0; reg < 4; ++reg) {
                int rl = w * 32 + mt * 16 + kg * 4 + reg;
                float h = fmaxf(acc[mt][nt][reg] + bv, 0.f);
                unsigned short hb = f2bf(h);
                Hh[rl][col] = hb;
                Hl[rl][col] = f2bf(h - bf2f(hb));
            }
        }
    __syncthreads();

    f32x4 acc2[2][4];
#pragma unroll
    for (int i = 0; i < 2; ++i)
#pragma unroll
        for (int j = 0; j < 4; ++j) acc2[i][j] = (f32x4){0.f, 0.f, 0.f, 0.f};

#pragma unroll
    for (int ks = 0; ks < 2; ++ks) {
        bf16x8 ah[2], al[2];
#pragma unroll
        for (int mt = 0; mt < 2; ++mt) {
            int rl = w * 32 + mt * 16 + r16;
            ah[mt] = *reinterpret_cast<const bf16x8*>(&Hh[rl][ks * 32 + kg * 8]);
            al[mt] = *reinterpret_cast<const bf16x8*>(&Hl[rl][ks * 32 + kg * 8]);
        }
#pragma unroll
        for (int nt = 0; nt < 4; ++nt) {
            const unsigned short* wb =
                Wlpk + (size_t)(((ks * 4 + nt) * 2)) * 512 + lane * 8;
            bf16x8 bh = *reinterpret_cast<const bf16x8*>(wb);
            bf16x8 blo = *reinterpret_cast<const bf16x8*>(wb + 512);
#pragma unroll
            for (int mt = 0; mt < 2; ++mt) {
                acc2[mt][nt] = __builtin_amdgcn_mfma_f32_16x16x32_bf16(ah[mt], bh,  acc2[mt][nt], 0, 0, 0);
                acc2[mt][nt] = __builtin_amdgcn_mfma_f32_16x16x32_bf16(ah[mt], blo, acc2[mt][nt], 0, 0, 0);
                acc2[mt][nt] = __builtin_amdgcn_mfma_f32_16x16x32_bf16(al[mt], bh,  acc2[mt][nt], 0, 0, 0);
            }
        }
    }

    // epilogue 2: out = (h2 + bl) * dg
#pragma unroll
    for (int mt = 0; mt < 2; ++mt)
#pragma unroll
        for (int nt = 0; nt < 4; ++nt) {
            int col = nt * 16 + r16;
            float bv = bl[col];
#pragma unroll
            for (int reg = 0; reg < 4; ++reg) {
                int rl = w * 32 + mt * 16 + kg * 4 + reg;
                if (m0 + rl < rowsEff) {
                    size_t idx = (size_t)(r0 + m0 + rl) * 64 + col;
                    outb[idx] = (acc2[mt][nt][reg] + bv) * dgb[idx];
                }
            }
        }
}

// ---------------------------------------------------------------------------
// pooling scatter: 16-lane group per nnz, float4 read + 4 atomics per lane.
// ---------------------------------------------------------------------------
__global__ __launch_bounds__(256) void pool_scatter(
        const int* __restrict__ prow, const int* __restrict__ pcol,
        const float* __restrict__ pval, const int* __restrict__ poolRk,
        const float* __restrict__ outb, float* __restrict__ out) {
    int t = blockIdx.x * 256 + threadIdx.x;
    int i = t >> 4, l16 = t & 15;
    if (i >= NPERM_C) return;
    int r = prow[i], c = pcol[i];
    float v = pval[i];
    int cr = poolRk[c] >> 1;
    float4 o4 = *reinterpret_cast<const float4*>(outb + (size_t)cr * 64 + l16 * 4);
    float* dst = out + (size_t)r * 64 + l16 * 4;
    atomicAdd(dst + 0, v * o4.x);
    atomicAdd(dst + 1, v * o4.y);
    atomicAdd(dst + 2, v * o4.z);
    atomicAdd(dst + 3, v * o4.w);
}

extern "C" void kernel_launch(void* const* d_in, const int* in_sizes, int n_in,
                              void* d_out, int out_size, void* d_ws, size_t ws_size,
                              hipStream_t stream) {
    const float* x       = (const float*)d_in[0];
    const float* efeat   = (const float*)d_in[1];
    const float* degs    = (const float*)d_in[2];
    const int*   n2p_row = (const int*)d_in[3];
    const int*   n2p_col = (const int*)d_in[4];
    const float* n2p_val = (const float*)d_in[5];
    const int*   e2p_row = (const int*)d_in[6];
    const int*   e2p_col = (const int*)d_in[7];
    const float* e2p_val = (const float*)d_in[8];
    const int*   pool_row = (const int*)d_in[9];
    const int*   pool_col = (const int*)d_in[10];
    const float* pool_val = (const float*)d_in[11];
    const float* weights = (const float*)d_in[12];
    const float* bias    = (const float*)d_in[13];
    const float* W0      = (const float*)d_in[14];
    const float* b0      = (const float*)d_in[15];
    const float* W1      = (const float*)d_in[16];
    const float* b1      = (const float*)d_in[17];
    const float* Wl      = (const float*)d_in[18];
    const float* bl      = (const float*)d_in[19];
    float* out = (float*)d_out;

    // workspace layout (4B elems)
    unsigned long long* suv = (unsigned long long*)d_ws;   // 16,000,000 (8M x 8B)
    int*   pOff     = (int*)(suv + 8000000);           //  4,000,064
    int*   pCur     = pOff + 4000064;                  //  4,000,000
    int*   bsum     = pCur + 4000000;                  //      2,048
    int*   poolCnt  = bsum + 2048;                     //    250,000
    int*   poolRk   = poolCnt + 250000;                //    250,000
    int*   bsum2    = poolRk + 250000;                 //        256
    int*   nActB    = bsum2 + 256;                     //         16
    unsigned short* Bpk  = (unsigned short*)(nActB + 16);   // 131072 us = 65536
    unsigned short* Wlpk = Bpk + 131072;                    //   8192 us =  4096
    float* degD = (float*)(Wlpk + 8192);               //  1,000,000
    float* dgb  = degD + 1000000;                      // 16,000,000
    float* outb = dgb;                                 // alias (same-idx RAW)
    unsigned short* nfH = (unsigned short*)(dgb + 16000000);

    const long long base_elems = 16000000LL + 4000064 + 4000000 + 2048 +
                                 250000 * 2 + 256 + 16 + 65536 + 4096 +
                                 1000000 + 16000000;   // 41,572,016
    long long availf = (long long)(ws_size / 4) - base_elems;
    long long chl = availf / 1024;   // per row: 2 planes * 16*64 * 2B = 4 KB
    if (chl > NPERM_C) chl = NPERM_C;
    int CH = (int)(chl & ~127LL);
    if (CH < 128) {
        hipMemsetAsync(d_out, 0, (size_t)out_size * 4, stream);
        return;
    }
    unsigned short* nfL = nfH + (size_t)CH * 1024;

    hipMemsetAsync(pCur, 0, (size_t)P_C * 4, stream);
    hipMemsetAsync(poolCnt, 0, (size_t)NPERM_C * 4, stream);
    hipMemsetAsync(out, 0, (size_t)G_C * 64 * 4, stream);

    repack_bpk<<<512, 256, 0, stream>>>(weights, Bpk);
    repack_wlpk<<<32, 256, 0, stream>>>(Wl, Wlpk);

    pool_hist<<<(NPERM_C + 255) / 256, 256, 0, stream>>>(pool_col, poolCnt);
    pool_scan_local<<<NB2, 256, 0, stream>>>(poolCnt, poolRk, bsum2);
    pool_scan_top<<<1, 256, 0, stream>>>(bsum2);
    pool_scan_add<<<NB2, 256, 0, stream>>>(poolCnt, poolRk, bsum2, nActB);

    hist<<<3907, 256, 0, stream>>>(n2p_row, e2p_row, poolRk, pCur);
    scan_local<<<NB1, 256, 0, stream>>>(pCur, pOff, bsum);
    scan_top<<<1, 256, 0, stream>>>(bsum);
    scan_add<<<NB1, 256, 0, stream>>>(pOff, bsum, pCur);
    scat<<<7813, 256, 0, stream>>>(n2p_row, n2p_col, n2p_val,
                                   e2p_row, e2p_col, e2p_val,
                                   poolRk, pCur, suv);

    for (int c0 = 0; c0 < NPERM_C; c0 += CH) {
        int rows = NPERM_C - c0; if (rows > CH) rows = CH;
        gather_nfeat<<<(rows + 3) / 4, 256, 0, stream>>>(
            suv, pOff, x, efeat, degs, nActB, nfH, nfL, degD, c0, rows);
        dg_gemm<<<(rows + 63) / 64, 256, 0, stream>>>(
            degD, W0, b0, W1, b1, nActB, dgb, c0, rows);
        gemm_mfma<<<(rows + 127) / 128, 256, 0, stream>>>(
            nfH, nfL, Bpk, Wlpk, bias, bl, dgb, nActB, outb, c0, rows);
    }

    pool_scatter<<<15625, 256, 0, stream>>>(pool_row, pool_col, pool_val,
                                            poolRk, outb, out);
}

// Round 10
// 1355.168 us; speedup vs baseline: 1.1297x; 1.1297x over previous
//
#include <hip/hip_runtime.h>

#define NPERM_C 250000
#define P_C     4000000          // slots = NPERM * 16
#define G_C     4096
#define NB1     1954             // ceil(P_C / 2048) big scan
#define NB2     123              // ceil(NPERM_C / 2048) pool scan

typedef __attribute__((ext_vector_type(8))) short bf16x8;
typedef __attribute__((ext_vector_type(4))) float f32x4;

static __device__ __forceinline__ unsigned short f2bf(float f) {
    unsigned u = __float_as_uint(f);
    unsigned r = (u + 0x7fffu + ((u >> 16) & 1u)) >> 16;   // RNE
    return (unsigned short)r;
}
static __device__ __forceinline__ float bf2f(unsigned short s) {
    return __uint_as_float(((unsigned)s) << 16);
}
static __device__ __forceinline__ unsigned long long pack4(ushort4 s) {
    return (unsigned long long)s.x | ((unsigned long long)s.y << 16) |
           ((unsigned long long)s.z << 32) | ((unsigned long long)s.w << 48);
}

// ---------------------------------------------------------------------------
// fragment-ordered split-bf16 weight tables
// ---------------------------------------------------------------------------
__global__ void repack_bpk(const float* __restrict__ w, unsigned short* __restrict__ bpk) {
    int o = blockIdx.x * 256 + threadIdx.x;          // 131072 total
    int j = o & 7, lane = (o >> 3) & 63, h = (o >> 9) & 1;
    int nt = (o >> 10) & 3, ks = (o >> 12) & 1, l = o >> 13;
    int b = ks * 32 + (lane >> 4) * 8 + j;
    int c = nt * 16 + (lane & 15);
    float wv = w[(b * 64 + c) * 16 + l];
    unsigned short hb = f2bf(wv);
    bpk[o] = (h == 0) ? hb : f2bf(wv - bf2f(hb));
}

__global__ void repack_wlpk(const float* __restrict__ wl, unsigned short* __restrict__ wpk) {
    int o = blockIdx.x * 256 + threadIdx.x;          // 8192 total
    int j = o & 7, lane = (o >> 3) & 63, h = (o >> 9) & 1;
    int nt = (o >> 10) & 3, ks = o >> 12;
    int k = ks * 32 + (lane >> 4) * 8 + j;
    int c2 = nt * 16 + (lane & 15);
    float wv = wl[c2 * 64 + k];
    unsigned short hb = f2bf(wv);
    wpk[o] = (h == 0) ? hb : f2bf(wv - bf2f(hb));
}

// ---------------------------------------------------------------------------
// pool reference histogram: poolCnt[c] = #times perm row c is pooled.
// ---------------------------------------------------------------------------
__global__ __launch_bounds__(256) void pool_hist(const int* __restrict__ pcol,
                                                 int* __restrict__ poolCnt) {
    int i = blockIdx.x * 256 + threadIdx.x;
    if (i < NPERM_C) atomicAdd(&poolCnt[pcol[i]], 1);
}

// active-row compaction scan (flag = cnt!=0), deterministic.
__global__ __launch_bounds__(256) void pool_scan_local(const int* __restrict__ poolCnt,
                                                       int* __restrict__ poolRk,
                                                       int* __restrict__ bsum2) {
    __shared__ int ts[256];
    int b = blockIdx.x, t = threadIdx.x;
    int base = b * 2048 + t * 8;
    int v[8]; int s = 0;
#pragma unroll
    for (int i = 0; i < 8; ++i) {
        int idx = base + i;
        v[i] = (idx < NPERM_C) ? (poolCnt[idx] != 0) : 0;
        s += v[i];
    }
    ts[t] = s;
    __syncthreads();
    for (int ofs = 1; ofs < 256; ofs <<= 1) {
        int xv = (t >= ofs) ? ts[t - ofs] : 0;
        __syncthreads();
        ts[t] += xv;
        __syncthreads();
    }
    int run = ts[t] - s;
    if (t == 255) bsum2[b] = ts[255];
#pragma unroll
    for (int i = 0; i < 8; ++i) {
        int idx = base + i;
        if (idx < NPERM_C) poolRk[idx] = run;
        run += v[i];
    }
}

__global__ void pool_scan_top(int* __restrict__ bsum2) {
    __shared__ int ts[256];
    int t = threadIdx.x;
    int v = (t < NB2) ? bsum2[t] : 0;
    ts[t] = v;
    __syncthreads();
    for (int ofs = 1; ofs < 256; ofs <<= 1) {
        int xv = (t >= ofs) ? ts[t - ofs] : 0;
        __syncthreads();
        ts[t] += xv;
        __syncthreads();
    }
    if (t < NB2) bsum2[t] = ts[t] - v;
}

// finalize: poolRk[idx] := ((rank)<<1) | activeFlag ; nActB[0] = #active
__global__ __launch_bounds__(256) void pool_scan_add(const int* __restrict__ poolCnt,
                                                     int* __restrict__ poolRk,
                                                     const int* __restrict__ bsum2,
                                                     int* __restrict__ nActB) {
    int b = blockIdx.x, t = threadIdx.x;
    int add = bsum2[b];
    int base = b * 2048 + t * 8;
#pragma unroll
    for (int i = 0; i < 8; ++i) {
        int idx = base + i;
        if (idx < NPERM_C) {
            int flag = poolCnt[idx] != 0;
            int o = poolRk[idx] + add;
            poolRk[idx] = (o << 1) | flag;
            if (idx == NPERM_C - 1) nActB[0] = o + flag;
        }
    }
}

// ---------------------------------------------------------------------------
// slot histogram over ACTIVE rows, compact slot space, 8 entries/thread.
// ---------------------------------------------------------------------------
__global__ __launch_bounds__(256) void hist(const int* __restrict__ r1,
                                            const int* __restrict__ r2,
                                            const int* __restrict__ poolRk,
                                            int* __restrict__ cnt) {
    int i8 = (blockIdx.x * 256 + threadIdx.x) * 8;
    if (i8 >= 2 * P_C) return;
    const int* src = (i8 < P_C) ? (r1 + i8) : (r2 + (i8 - P_C));
    int4 ra = *reinterpret_cast<const int4*>(src);
    int4 rb = *reinterpret_cast<const int4*>(src + 4);
    int rr[8] = {ra.x, ra.y, ra.z, ra.w, rb.x, rb.y, rb.z, rb.w};
#pragma unroll
    for (int q = 0; q < 8; ++q) {
        int info = poolRk[rr[q] >> 4];
        if (info & 1) atomicAdd(&cnt[(info >> 1) * 16 + (rr[q] & 15)], 1);
    }
}

// big exclusive scan over 4M slot counts.
__global__ __launch_bounds__(256) void scan_local(const int* __restrict__ cnt,
                                                  int* __restrict__ off,
                                                  int* __restrict__ bsum) {
    __shared__ int ts[256];
    int b = blockIdx.x, t = threadIdx.x;
    int base = b * 2048 + t * 8;
    int v[8]; int s = 0;
#pragma unroll
    for (int i = 0; i < 8; ++i) {
        int idx = base + i;
        v[i] = (idx < P_C) ? cnt[idx] : 0;
        s += v[i];
    }
    ts[t] = s;
    __syncthreads();
    for (int ofs = 1; ofs < 256; ofs <<= 1) {
        int xv = (t >= ofs) ? ts[t - ofs] : 0;
        __syncthreads();
        ts[t] += xv;
        __syncthreads();
    }
    int run = ts[t] - s;
    if (t == 255) bsum[b] = ts[255];
#pragma unroll
    for (int i = 0; i < 8; ++i) {
        int idx = base + i;
        if (idx < P_C) off[idx] = run;
        run += v[i];
    }
}

__global__ void scan_top(int* __restrict__ bsum) {
    __shared__ int ts[256];
    int t = threadIdx.x;
    int base = t * 8;
    int v[8]; int s = 0;
#pragma unroll
    for (int i = 0; i < 8; ++i) {
        int idx = base + i;
        v[i] = (idx < NB1) ? bsum[idx] : 0;
        s += v[i];
    }
    ts[t] = s;
    __syncthreads();
    for (int ofs = 1; ofs < 256; ofs <<= 1) {
        int xv = (t >= ofs) ? ts[t - ofs] : 0;
        __syncthreads();
        ts[t] += xv;
        __syncthreads();
    }
    int run = ts[t] - s;
#pragma unroll
    for (int i = 0; i < 8; ++i) {
        int idx = base + i;
        if (idx < NB1) bsum[idx] = run;
        run += v[i];
    }
}

__global__ __launch_bounds__(256) void scan_add(int* __restrict__ off,
                                                const int* __restrict__ bsum,
                                                int* __restrict__ cur) {
    int b = blockIdx.x, t = threadIdx.x;
    int add = bsum[b];
    int base = b * 2048 + t * 8;
#pragma unroll
    for (int i = 0; i < 8; ++i) {
        int idx = base + i;
        if (idx < P_C) {
            int o = off[idx] + add;
            if (idx == P_C - 1) off[P_C] = o + cur[idx];  // cur still holds count
            off[idx] = o;
            cur[idx] = o;
        }
    }
}

// ---------------------------------------------------------------------------
// scatter active entries to sorted position, 2 entries/thread, nt stores.
// (round-8 configuration — 4/thread regressed: fewer latency-hiding chains)
// ---------------------------------------------------------------------------
__global__ __launch_bounds__(256) void scat(
        const int* __restrict__ r1, const int* __restrict__ c1, const float* __restrict__ v1,
        const int* __restrict__ r2, const int* __restrict__ c2, const float* __restrict__ v2,
        const int* __restrict__ poolRk,
        int* __restrict__ cur, unsigned long long* __restrict__ suv) {
    int i2 = (blockIdx.x * 256 + threadIdx.x) * 2;
    if (i2 >= 2 * P_C) return;
    const int* rr; const int* cc; const float* vv; unsigned srcbit; int base;
    if (i2 < P_C) { rr = r1; cc = c1; vv = v1; srcbit = 0u; base = i2; }
    else          { rr = r2; cc = c2; vv = v2; srcbit = 0x100000u; base = i2 - P_C; }
    int2 r = *reinterpret_cast<const int2*>(rr + base);
    int2 c = *reinterpret_cast<const int2*>(cc + base);
    float2 v = *reinterpret_cast<const float2*>(vv + base);
    {
        int info = poolRk[r.x >> 4];
        if (info & 1) {
            int pos = atomicAdd(&cur[(info >> 1) * 16 + (r.x & 15)], 1);
            unsigned long long e = (unsigned long long)((unsigned)c.x | srcbit) |
                                   ((unsigned long long)__float_as_uint(v.x) << 32);
            __builtin_nontemporal_store(e, suv + pos);
        }
    }
    {
        int info = poolRk[r.y >> 4];
        if (info & 1) {
            int pos = atomicAdd(&cur[(info >> 1) * 16 + (r.y & 15)], 1);
            unsigned long long e = (unsigned long long)((unsigned)c.y | srcbit) |
                                   ((unsigned long long)__float_as_uint(v.y) << 32);
            __builtin_nontemporal_store(e, suv + pos);
        }
    }
}

// ---------------------------------------------------------------------------
// CSR gather: block = 4 compact rows, 16 groups of 16 lanes; each group owns
// the 4 consecutive-slot chains of one (row, slot-quad). 4 independent load
// chains interleaved. nt loads for suv, nt stores for planes.
// ---------------------------------------------------------------------------
__global__ __launch_bounds__(256) void gather_nfeat(
        const unsigned long long* __restrict__ suv, const int* __restrict__ pOff,
        const float* __restrict__ x, const float* __restrict__ efeat,
        const float* __restrict__ degs, const int* __restrict__ nActB,
        unsigned short* __restrict__ nfH, unsigned short* __restrict__ nfL,
        float* __restrict__ degD, int row0, int rows) {
    int nAct = nActB[0];
    int t = threadIdx.x;
    int gid = t >> 4;            // 0..15  (wave = gid>>2 = row)
    int t16 = t & 15;
    int r4 = gid >> 2;           // row within block (wave-uniform)
    int q4 = gid & 3;            // slot quad
    int cr = row0 + blockIdx.x * 4 + r4;
    int rend = row0 + rows; if (rend > nAct) rend = nAct;
    if (cr >= rend) return;      // wave-uniform exit
    int sBase = cr * 16 + q4 * 4;
    int4 bo = *reinterpret_cast<const int4*>(pOff + sBase);
    int e4 = pOff[sBase + 4];
    int i0 = bo.x, e0 = bo.y;
    int i1 = bo.y, e1 = bo.z;
    int i2 = bo.z, e2 = bo.w;
    int i3 = bo.w, e3 = e4;
    float4 a0 = {0,0,0,0}, a1 = {0,0,0,0}, a2 = {0,0,0,0}, a3 = {0,0,0,0};
    float dq = 0.f;              // degree accum for sub-chain q4
    while ((i0 < e0) | (i1 < e1) | (i2 < e2) | (i3 < e3)) {
        bool h0 = i0 < e0, h1 = i1 < e1, h2 = i2 < e2, h3 = i3 < e3;
        unsigned long long k0, k1, k2, k3;
        if (h0) k0 = __builtin_nontemporal_load(suv + i0);
        if (h1) k1 = __builtin_nontemporal_load(suv + i1);
        if (h2) k2 = __builtin_nontemporal_load(suv + i2);
        if (h3) k3 = __builtin_nontemporal_load(suv + i3);
        if (h0) {
            unsigned k = (unsigned)k0; float v = __uint_as_float((unsigned)(k0 >> 32));
            const float* f = (k & 0x100000u) ? efeat : x;
            float4 fv = *reinterpret_cast<const float4*>(
                f + (size_t)(k & 0xFFFFFu) * 64 + t16 * 4);
            a0.x = fmaf(v, fv.x, a0.x); a0.y = fmaf(v, fv.y, a0.y);
            a0.z = fmaf(v, fv.z, a0.z); a0.w = fmaf(v, fv.w, a0.w);
            if (q4 == 0 && !(k & 0x100000u)) dq = fmaf(v, degs[k & 0xFFFFFu], dq);
            ++i0;
        }
        if (h1) {
            unsigned k = (unsigned)k1; float v = __uint_as_float((unsigned)(k1 >> 32));
            const float* f = (k & 0x100000u) ? efeat : x;
            float4 fv = *reinterpret_cast<const float4*>(
                f + (size_t)(k & 0xFFFFFu) * 64 + t16 * 4);
            a1.x = fmaf(v, fv.x, a1.x); a1.y = fmaf(v, fv.y, a1.y);
            a1.z = fmaf(v, fv.z, a1.z); a1.w = fmaf(v, fv.w, a1.w);
            if (q4 == 1 && !(k & 0x100000u)) dq = fmaf(v, degs[k & 0xFFFFFu], dq);
            ++i1;
        }
        if (h2) {
            unsigned k = (unsigned)k2; float v = __uint_as_float((unsigned)(k2 >> 32));
            const float* f = (k & 0x100000u) ? efeat : x;
            float4 fv = *reinterpret_cast<const float4*>(
                f + (size_t)(k & 0xFFFFFu) * 64 + t16 * 4);
            a2.x = fmaf(v, fv.x, a2.x); a2.y = fmaf(v, fv.y, a2.y);
            a2.z = fmaf(v, fv.z, a2.z); a2.w = fmaf(v, fv.w, a2.w);
            if (q4 == 2 && !(k & 0x100000u)) dq = fmaf(v, degs[k & 0xFFFFFu], dq);
            ++i2;
        }
        if (h3) {
            unsigned k = (unsigned)k3; float v = __uint_as_float((unsigned)(k3 >> 32));
            const float* f = (k & 0x100000u) ? efeat : x;
            float4 fv = *reinterpret_cast<const float4*>(
                f + (size_t)(k & 0xFFFFFu) * 64 + t16 * 4);
            a3.x = fmaf(v, fv.x, a3.x); a3.y = fmaf(v, fv.y, a3.y);
            a3.z = fmaf(v, fv.z, a3.z); a3.w = fmaf(v, fv.w, a3.w);
            if (q4 == 3 && !(k & 0x100000u)) dq = fmaf(v, degs[k & 0xFFFFFu], dq);
            ++i3;
        }
    }
    size_t o = ((size_t)(cr - row0) * 16 + q4 * 4) * 64 + t16 * 4;
    float4 as[4] = {a0, a1, a2, a3};
#pragma unroll
    for (int c = 0; c < 4; ++c) {
        ushort4 h4, l4;
        h4.x = f2bf(as[c].x); l4.x = f2bf(as[c].x - bf2f(h4.x));
        h4.y = f2bf(as[c].y); l4.y = f2bf(as[c].y - bf2f(h4.y));
        h4.z = f2bf(as[c].z); l4.z = f2bf(as[c].z - bf2f(h4.z));
        h4.w = f2bf(as[c].w); l4.w = f2bf(as[c].w - bf2f(h4.w));
        __builtin_nontemporal_store(pack4(h4),
            reinterpret_cast<unsigned long long*>(nfH + o + (size_t)c * 64));
        __builtin_nontemporal_store(pack4(l4),
            reinterpret_cast<unsigned long long*>(nfL + o + (size_t)c * 64));
    }
    if (t16 == 0) degD[(size_t)cr * 4 + q4] = dq;
}

// ---------------------------------------------------------------------------
// degree-gate MLP over compact rows [r0, min(r0+rows, nAct)).
// ---------------------------------------------------------------------------
__global__ __launch_bounds__(256) void dg_gemm(
        const float* __restrict__ degD,
        const float* __restrict__ W0, const float* __restrict__ b0,
        const float* __restrict__ W1, const float* __restrict__ b1,
        const int* __restrict__ nActB,
        float* __restrict__ dgb, int r0, int rows) {
    __shared__ float hidT[128][68];   // [h][r]
    __shared__ float w1T[128][68];    // [h][c]
    __shared__ float dloc[64][4];
    __shared__ float w0s[128][5];
    int nAct = nActB[0];
    int rend = r0 + rows; if (rend > nAct) rend = nAct;
    int t = threadIdx.x;
    int m0 = r0 + blockIdx.x * 64;
    if (m0 >= rend) return;

    {
        int r = t >> 2, j = t & 3;
        int gr = m0 + r; if (gr >= rend) gr = rend - 1;
        dloc[r][j] = degD[(size_t)gr * 4 + j];
    }
    if (t < 128) {
        w0s[t][0] = W0[t * 4 + 0]; w0s[t][1] = W0[t * 4 + 1];
        w0s[t][2] = W0[t * 4 + 2]; w0s[t][3] = W0[t * 4 + 3];
        w0s[t][4] = b0[t];
    }
    for (int s = 0; s < 32; ++s) {
        int idx = t + s * 256;
        w1T[idx & 127][idx >> 7] = W1[idx];
    }
    __syncthreads();
    for (int s = 0; s < 32; ++s) {
        int idx = t + s * 256;
        int h = idx & 127, r = idx >> 7;
        float v = w0s[h][4] + dloc[r][0] * w0s[h][0] + dloc[r][1] * w0s[h][1]
                            + dloc[r][2] * w0s[h][2] + dloc[r][3] * w0s[h][3];
        hidT[h][r] = fmaxf(v, 0.f);
    }
    __syncthreads();

    int tm = t >> 4, tn = t & 15;
    float acc[4][4] = {};
#pragma unroll 8
    for (int k = 0; k < 128; ++k) {
        float4 a = *reinterpret_cast<const float4*>(&hidT[k][tm * 4]);
        float4 b = *reinterpret_cast<const float4*>(&w1T[k][tn * 4]);
        acc[0][0] = fmaf(a.x, b.x, acc[0][0]); acc[0][1] = fmaf(a.x, b.y, acc[0][1]);
        acc[0][2] = fmaf(a.x, b.z, acc[0][2]); acc[0][3] = fmaf(a.x, b.w, acc[0][3]);
        acc[1][0] = fmaf(a.y, b.x, acc[1][0]); acc[1][1] = fmaf(a.y, b.y, acc[1][1]);
        acc[1][2] = fmaf(a.y, b.z, acc[1][2]); acc[1][3] = fmaf(a.y, b.w, acc[1][3]);
        acc[2][0] = fmaf(a.z, b.x, acc[2][0]); acc[2][1] = fmaf(a.z, b.y, acc[2][1]);
        acc[2][2] = fmaf(a.z, b.z, acc[2][2]); acc[2][3] = fmaf(a.z, b.w, acc[2][3]);
        acc[3][0] = fmaf(a.w, b.x, acc[3][0]); acc[3][1] = fmaf(a.w, b.y, acc[3][1]);
        acc[3][2] = fmaf(a.w, b.z, acc[3][2]); acc[3][3] = fmaf(a.w, b.w, acc[3][3]);
    }
    float bb[4] = {b1[tn * 4 + 0], b1[tn * 4 + 1], b1[tn * 4 + 2], b1[tn * 4 + 3]};
#pragma unroll
    for (int i = 0; i < 4; ++i) {
        int grow = m0 + tm * 4 + i;
        if (grow < rend) {
            float4 o = {acc[i][0] + bb[0], acc[i][1] + bb[1],
                        acc[i][2] + bb[2], acc[i][3] + bb[3]};
            *reinterpret_cast<float4*>(&dgb[(size_t)grow * 64 + tn * 4]) = o;
        }
    }
}

// ---------------------------------------------------------------------------
// MFMA einsum + epilogue (split-bf16, 3 products) over compact rows.
// ---------------------------------------------------------------------------
__global__ __launch_bounds__(256) void gemm_mfma(
        const unsigned short* __restrict__ nfH, const unsigned short* __restrict__ nfL,
        const unsigned short* __restrict__ Bpk, const unsigned short* __restrict__ Wlpk,
        const float* __restrict__ bias, const float* __restrict__ bl,
        const float* __restrict__ dgb, const int* __restrict__ nActB,
        float* __restrict__ outb, int r0, int rows) {
    __shared__ unsigned short Hh[128][72];
    __shared__ unsigned short Hl[128][72];
    int nAct = nActB[0];
    int rowsEff = rows; if (r0 + rowsEff > nAct) rowsEff = nAct - r0;
    int t = threadIdx.x, lane = t & 63, w = t >> 6;
    int m0 = blockIdx.x * 128;
    if (m0 >= rowsEff) return;
    int r16 = lane & 15, kg = lane >> 4;

    f32x4 acc[2][4];
#pragma unroll
    for (int i = 0; i < 2; ++i)
#pragma unroll
        for (int j = 0; j < 4; ++j) acc[i][j] = (f32x4){0.f, 0.f, 0.f, 0.f};

    for (int l = 0; l < 16; ++l) {
#pragma unroll
        for (int ks = 0; ks < 2; ++ks) {
            bf16x8 ah[2], al[2];
#pragma unroll
            for (int mt = 0; mt < 2; ++mt) {
                int lr = m0 + w * 32 + mt * 16 + r16;
                if (lr >= rowsEff) lr = rowsEff - 1;
                size_t off = ((size_t)lr * 16 + l) * 64 + ks * 32 + kg * 8;
                ah[mt] = *reinterpret_cast<const bf16x8*>(nfH + off);
                al[mt] = *reinterpret_cast<const bf16x8*>(nfL + off);
            }
#pragma unroll
            for (int nt = 0; nt < 4; ++nt) {
                const unsigned short* bb =
                    Bpk + (size_t)(((l * 2 + ks) * 4 + nt) * 2) * 512 + lane * 8;
                bf16x8 bh = *reinterpret_cast<const bf16x8*>(bb);
                bf16x8 blo = *reinterpret_cast<const bf16x8*>(bb + 512);
#pragma unroll
                for (int mt = 0; mt < 2; ++mt) {
                    acc[mt][nt] = __builtin_amdgcn_mfma_f32_16x16x32_bf16(ah[mt], bh,  acc[mt][nt], 0, 0, 0);
                    acc[mt][nt] = __builtin_amdgcn_mfma_f32_16x16x32_bf16(ah[mt], blo, acc[mt][nt], 0, 0, 0);
                    acc[mt][nt] = __builtin_amdgcn_mfma_f32_16x16x32_bf16(al[mt], bh,  acc[mt][nt], 0, 0, 0);
                }
            }
        }
    }

    // epilogue 1: h = relu(acc + bias) -> split-bf16 LDS planes
#pragma unroll
    for (int mt = 0; mt < 2; ++mt)
#pragma unroll
        for (int nt = 0; nt < 4; ++nt) {
            int col = nt * 16 + r16;
            float bv = bias[col];
#pragma unroll
            for (int reg = 0; reg < 4; ++reg) {
                int rl = w * 32 + mt * 16 + kg * 4 + reg;
                float h = fmaxf(acc[mt][nt][reg] + bv, 0.f);
                unsigned short hb = f2bf(h);
                Hh[rl][col] = hb;
                Hl[rl][col] = f2bf(h - bf2f(hb));
            }
        }
    __syncthreads();

    f32x4 acc2[2][4];
#pragma unroll
    for (int i = 0; i < 2; ++i)
#pragma unroll
        for (int j = 0; j < 4; ++j) acc2[i][j] = (f32x4){0.f, 0.f, 0.f, 0.f};

#pragma unroll
    for (int ks = 0; ks < 2; ++ks) {
        bf16x8 ah[2], al[2];
#pragma unroll
        for (int mt = 0; mt < 2; ++mt) {
            int rl = w * 32 + mt * 16 + r16;
            ah[mt] = *reinterpret_cast<const bf16x8*>(&Hh[rl][ks * 32 + kg * 8]);
            al[mt] = *reinterpret_cast<const bf16x8*>(&Hl[rl][ks * 32 + kg * 8]);
        }
#pragma unroll
        for (int nt = 0; nt < 4; ++nt) {
            const unsigned short* wb =
                Wlpk + (size_t)(((ks * 4 + nt) * 2)) * 512 + lane * 8;
            bf16x8 bh = *reinterpret_cast<const bf16x8*>(wb);
            bf16x8 blo = *reinterpret_cast<const bf16x8*>(wb + 512);
#pragma unroll
            for (int mt = 0; mt < 2; ++mt) {
                acc2[mt][nt] = __builtin_amdgcn_mfma_f32_16x16x32_bf16(ah[mt], bh,  acc2[mt][nt], 0, 0, 0);
                acc2[mt][nt] = __builtin_amdgcn_mfma_f32_16x16x32_bf16(ah[mt], blo, acc2[mt][nt], 0, 0, 0);
                acc2[mt][nt] = __builtin_amdgcn_mfma_f32_16x16x32_bf16(al[mt], bh,  acc2[mt][nt], 0, 0, 0);
            }
        }
    }

    // epilogue 2: out = (h2 + bl) * dg
#pragma unroll
    for (int mt = 0; mt < 2; ++mt)
#pragma unroll
        for (int nt = 0; nt < 4; ++nt) {
            int col = nt * 16 + r16;
            float bv = bl[col];
#pragma unroll
            for (int reg = 0; reg < 4; ++reg) {
                int rl = w * 32 + mt * 16 + kg * 4 + reg;
                if (m0 + rl < rowsEff) {
                    size_t idx = (size_t)(r0 + m0 + rl) * 64 + col;
                    outb[idx] = (acc2[mt][nt][reg] + bv) * dgb[idx];
                }
            }
        }
}

// ---------------------------------------------------------------------------
// pooling scatter: one 64-lane wave per nnz, 1 atomic per lane (round-8 cfg).
// ---------------------------------------------------------------------------
__global__ __launch_bounds__(256) void pool_scatter(
        const int* __restrict__ prow, const int* __restrict__ pcol,
        const float* __restrict__ pval, const int* __restrict__ poolRk,
        const float* __restrict__ outb, float* __restrict__ out) {
    int t = blockIdx.x * 256 + threadIdx.x;
    int i = t >> 6, d = t & 63;
    if (i >= NPERM_C) return;
    int r = prow[i], c = pcol[i];
    float v = pval[i];
    int cr = poolRk[c] >> 1;
    atomicAdd(&out[(size_t)r * 64 + d], v * outb[(size_t)cr * 64 + d]);
}

extern "C" void kernel_launch(void* const* d_in, const int* in_sizes, int n_in,
                              void* d_out, int out_size, void* d_ws, size_t ws_size,
                              hipStream_t stream) {
    const float* x       = (const float*)d_in[0];
    const float* efeat   = (const float*)d_in[1];
    const float* degs    = (const float*)d_in[2];
    const int*   n2p_row = (const int*)d_in[3];
    const int*   n2p_col = (const int*)d_in[4];
    const float* n2p_val = (const float*)d_in[5];
    const int*   e2p_row = (const int*)d_in[6];
    const int*   e2p_col = (const int*)d_in[7];
    const float* e2p_val = (const float*)d_in[8];
    const int*   pool_row = (const int*)d_in[9];
    const int*   pool_col = (const int*)d_in[10];
    const float* pool_val = (const float*)d_in[11];
    const float* weights = (const float*)d_in[12];
    const float* bias    = (const float*)d_in[13];
    const float* W0      = (const float*)d_in[14];
    const float* b0      = (const float*)d_in[15];
    const float* W1      = (const float*)d_in[16];
    const float* b1      = (const float*)d_in[17];
    const float* Wl      = (const float*)d_in[18];
    const float* bl      = (const float*)d_in[19];
    float* out = (float*)d_out;

    // workspace layout (4B elems)
    unsigned long long* suv = (unsigned long long*)d_ws;   // 16,000,000 (8M x 8B)
    int*   pOff     = (int*)(suv + 8000000);           //  4,000,064
    int*   pCur     = pOff + 4000064;                  //  4,000,000
    int*   bsum     = pCur + 4000000;                  //      2,048
    int*   poolCnt  = bsum + 2048;                     //    250,000
    int*   poolRk   = poolCnt + 250000;                //    250,000
    int*   bsum2    = poolRk + 250000;                 //        256
    int*   nActB    = bsum2 + 256;                     //         16
    unsigned short* Bpk  = (unsigned short*)(nActB + 16);   // 131072 us = 65536
    unsigned short* Wlpk = Bpk + 131072;                    //   8192 us =  4096
    float* degD = (float*)(Wlpk + 8192);               //  1,000,000
    float* dgb  = degD + 1000000;                      // 16,000,000
    float* outb = dgb;                                 // alias (same-idx RAW)
    unsigned short* nfH = (unsigned short*)(dgb + 16000000);

    const long long base_elems = 16000000LL + 4000064 + 4000000 + 2048 +
                                 250000 * 2 + 256 + 16 + 65536 + 4096 +
                                 1000000 + 16000000;   // 41,572,016
    long long availf = (long long)(ws_size / 4) - base_elems;
    long long chl = availf / 1024;   // per row: 2 planes * 16*64 * 2B = 4 KB
    if (chl > NPERM_C) chl = NPERM_C;
    int CH = (int)(chl & ~127LL);
    if (CH < 128) {
        hipMemsetAsync(d_out, 0, (size_t)out_size * 4, stream);
        return;
    }
    unsigned short* nfL = nfH + (size_t)CH * 1024;

    hipMemsetAsync(pCur, 0, (size_t)P_C * 4, stream);
    hipMemsetAsync(poolCnt, 0, (size_t)NPERM_C * 4, stream);
    hipMemsetAsync(out, 0, (size_t)G_C * 64 * 4, stream);

    repack_bpk<<<512, 256, 0, stream>>>(weights, Bpk);
    repack_wlpk<<<32, 256, 0, stream>>>(Wl, Wlpk);

    pool_hist<<<(NPERM_C + 255) / 256, 256, 0, stream>>>(pool_col, poolCnt);
    pool_scan_local<<<NB2, 256, 0, stream>>>(poolCnt, poolRk, bsum2);
    pool_scan_top<<<1, 256, 0, stream>>>(bsum2);
    pool_scan_add<<<NB2, 256, 0, stream>>>(poolCnt, poolRk, bsum2, nActB);

    hist<<<3907, 256, 0, stream>>>(n2p_row, e2p_row, poolRk, pCur);
    scan_local<<<NB1, 256, 0, stream>>>(pCur, pOff, bsum);
    scan_top<<<1, 256, 0, stream>>>(bsum);
    scan_add<<<NB1, 256, 0, stream>>>(pOff, bsum, pCur);
    scat<<<15625, 256, 0, stream>>>(n2p_row, n2p_col, n2p_val,
                                    e2p_row, e2p_col, e2p_val,
                                    poolRk, pCur, suv);

    for (int c0 = 0; c0 < NPERM_C; c0 += CH) {
        int rows = NPERM_C - c0; if (rows > CH) rows = CH;
        gather_nfeat<<<(rows + 3) / 4, 256, 0, stream>>>(
            suv, pOff, x, efeat, degs, nActB, nfH, nfL, degD, c0, rows);
        dg_gemm<<<(rows + 63) / 64, 256, 0, stream>>>(
            degD, W0, b0, W1, b1, nActB, dgb, c0, rows);
        gemm_mfma<<<(rows + 127) / 128, 256, 0, stream>>>(
            nfH, nfL, Bpk, Wlpk, bias, bl, dgb, nActB, outb, c0, rows);
    }

    pool_scatter<<<62500, 256, 0, stream>>>(pool_row, pool_col, pool_val,
                                            poolRk, outb, out);
}

// Round 11
// 1348.325 us; speedup vs baseline: 1.1355x; 1.0051x over previous
//
#include <hip/hip_runtime.h>

#define NPERM_C 250000
#define P_C     4000000          // slots = NPERM * 16
#define G_C     4096
#define NB1     1954             // ceil(P_C / 2048) big scan
#define NB2     123              // ceil(NPERM_C / 2048) pool scan

typedef __attribute__((ext_vector_type(8))) short bf16x8;
typedef __attribute__((ext_vector_type(4))) float f32x4;

static __device__ __forceinline__ unsigned short f2bf(float f) {
    unsigned u = __float_as_uint(f);
    unsigned r = (u + 0x7fffu + ((u >> 16) & 1u)) >> 16;   // RNE
    return (unsigned short)r;
}
static __device__ __forceinline__ float bf2f(unsigned short s) {
    return __uint_as_float(((unsigned)s) << 16);
}
static __device__ __forceinline__ unsigned long long pack4(ushort4 s) {
    return (unsigned long long)s.x | ((unsigned long long)s.y << 16) |
           ((unsigned long long)s.z << 32) | ((unsigned long long)s.w << 48);
}

// ---------------------------------------------------------------------------
// fragment-ordered split-bf16 weight tables
// ---------------------------------------------------------------------------
__global__ void repack_bpk(const float* __restrict__ w, unsigned short* __restrict__ bpk) {
    int o = blockIdx.x * 256 + threadIdx.x;          // 131072 total
    int j = o & 7, lane = (o >> 3) & 63, h = (o >> 9) & 1;
    int nt = (o >> 10) & 3, ks = (o >> 12) & 1, l = o >> 13;
    int b = ks * 32 + (lane >> 4) * 8 + j;
    int c = nt * 16 + (lane & 15);
    float wv = w[(b * 64 + c) * 16 + l];
    unsigned short hb = f2bf(wv);
    bpk[o] = (h == 0) ? hb : f2bf(wv - bf2f(hb));
}

__global__ void repack_wlpk(const float* __restrict__ wl, unsigned short* __restrict__ wpk) {
    int o = blockIdx.x * 256 + threadIdx.x;          // 8192 total
    int j = o & 7, lane = (o >> 3) & 63, h = (o >> 9) & 1;
    int nt = (o >> 10) & 3, ks = o >> 12;
    int k = ks * 32 + (lane >> 4) * 8 + j;
    int c2 = nt * 16 + (lane & 15);
    float wv = wl[c2 * 64 + k];
    unsigned short hb = f2bf(wv);
    wpk[o] = (h == 0) ? hb : f2bf(wv - bf2f(hb));
}

// ---------------------------------------------------------------------------
// pool reference histogram: poolCnt[c] = #times perm row c is pooled.
// ---------------------------------------------------------------------------
__global__ __launch_bounds__(256) void pool_hist(const int* __restrict__ pcol,
                                                 int* __restrict__ poolCnt) {
    int i = blockIdx.x * 256 + threadIdx.x;
    if (i < NPERM_C) atomicAdd(&poolCnt[pcol[i]], 1);
}

// active-row compaction scan (flag = cnt!=0), deterministic.
__global__ __launch_bounds__(256) void pool_scan_local(const int* __restrict__ poolCnt,
                                                       int* __restrict__ poolRk,
                                                       int* __restrict__ bsum2) {
    __shared__ int ts[256];
    int b = blockIdx.x, t = threadIdx.x;
    int base = b * 2048 + t * 8;
    int v[8]; int s = 0;
#pragma unroll
    for (int i = 0; i < 8; ++i) {
        int idx = base + i;
        v[i] = (idx < NPERM_C) ? (poolCnt[idx] != 0) : 0;
        s += v[i];
    }
    ts[t] = s;
    __syncthreads();
    for (int ofs = 1; ofs < 256; ofs <<= 1) {
        int xv = (t >= ofs) ? ts[t - ofs] : 0;
        __syncthreads();
        ts[t] += xv;
        __syncthreads();
    }
    int run = ts[t] - s;
    if (t == 255) bsum2[b] = ts[255];
#pragma unroll
    for (int i = 0; i < 8; ++i) {
        int idx = base + i;
        if (idx < NPERM_C) poolRk[idx] = run;
        run += v[i];
    }
}

__global__ void pool_scan_top(int* __restrict__ bsum2) {
    __shared__ int ts[256];
    int t = threadIdx.x;
    int v = (t < NB2) ? bsum2[t] : 0;
    ts[t] = v;
    __syncthreads();
    for (int ofs = 1; ofs < 256; ofs <<= 1) {
        int xv = (t >= ofs) ? ts[t - ofs] : 0;
        __syncthreads();
        ts[t] += xv;
        __syncthreads();
    }
    if (t < NB2) bsum2[t] = ts[t] - v;
}

// finalize: poolRk[idx] := ((rank)<<1) | activeFlag ; nActB[0] = #active
__global__ __launch_bounds__(256) void pool_scan_add(const int* __restrict__ poolCnt,
                                                     int* __restrict__ poolRk,
                                                     const int* __restrict__ bsum2,
                                                     int* __restrict__ nActB) {
    int b = blockIdx.x, t = threadIdx.x;
    int add = bsum2[b];
    int base = b * 2048 + t * 8;
#pragma unroll
    for (int i = 0; i < 8; ++i) {
        int idx = base + i;
        if (idx < NPERM_C) {
            int flag = poolCnt[idx] != 0;
            int o = poolRk[idx] + add;
            poolRk[idx] = (o << 1) | flag;
            if (idx == NPERM_C - 1) nActB[0] = o + flag;
        }
    }
}

// ---------------------------------------------------------------------------
// slot histogram over ACTIVE rows, compact slot space, 8 entries/thread.
// ---------------------------------------------------------------------------
__global__ __launch_bounds__(256) void hist(const int* __restrict__ r1,
                                            const int* __restrict__ r2,
                                            const int* __restrict__ poolRk,
                                            int* __restrict__ cnt) {
    int i8 = (blockIdx.x * 256 + threadIdx.x) * 8;
    if (i8 >= 2 * P_C) return;
    const int* src = (i8 < P_C) ? (r1 + i8) : (r2 + (i8 - P_C));
    int4 ra = *reinterpret_cast<const int4*>(src);
    int4 rb = *reinterpret_cast<const int4*>(src + 4);
    int rr[8] = {ra.x, ra.y, ra.z, ra.w, rb.x, rb.y, rb.z, rb.w};
#pragma unroll
    for (int q = 0; q < 8; ++q) {
        int info = poolRk[rr[q] >> 4];
        if (info & 1) atomicAdd(&cnt[(info >> 1) * 16 + (rr[q] & 15)], 1);
    }
}

// big exclusive scan over 4M slot counts.
__global__ __launch_bounds__(256) void scan_local(const int* __restrict__ cnt,
                                                  int* __restrict__ off,
                                                  int* __restrict__ bsum) {
    __shared__ int ts[256];
    int b = blockIdx.x, t = threadIdx.x;
    int base = b * 2048 + t * 8;
    int v[8]; int s = 0;
#pragma unroll
    for (int i = 0; i < 8; ++i) {
        int idx = base + i;
        v[i] = (idx < P_C) ? cnt[idx] : 0;
        s += v[i];
    }
    ts[t] = s;
    __syncthreads();
    for (int ofs = 1; ofs < 256; ofs <<= 1) {
        int xv = (t >= ofs) ? ts[t - ofs] : 0;
        __syncthreads();
        ts[t] += xv;
        __syncthreads();
    }
    int run = ts[t] - s;
    if (t == 255) bsum[b] = ts[255];
#pragma unroll
    for (int i = 0; i < 8; ++i) {
        int idx = base + i;
        if (idx < P_C) off[idx] = run;
        run += v[i];
    }
}

__global__ void scan_top(int* __restrict__ bsum) {
    __shared__ int ts[256];
    int t = threadIdx.x;
    int base = t * 8;
    int v[8]; int s = 0;
#pragma unroll
    for (int i = 0; i < 8; ++i) {
        int idx = base + i;
        v[i] = (idx < NB1) ? bsum[idx] : 0;
        s += v[i];
    }
    ts[t] = s;
    __syncthreads();
    for (int ofs = 1; ofs < 256; ofs <<= 1) {
        int xv = (t >= ofs) ? ts[t - ofs] : 0;
        __syncthreads();
        ts[t] += xv;
        __syncthreads();
    }
    int run = ts[t] - s;
#pragma unroll
    for (int i = 0; i < 8; ++i) {
        int idx = base + i;
        if (idx < NB1) bsum[idx] = run;
        run += v[i];
    }
}

__global__ __launch_bounds__(256) void scan_add(int* __restrict__ off,
                                                const int* __restrict__ bsum,
                                                int* __restrict__ cur) {
    int b = blockIdx.x, t = threadIdx.x;
    int add = bsum[b];
    int base = b * 2048 + t * 8;
#pragma unroll
    for (int i = 0; i < 8; ++i) {
        int idx = base + i;
        if (idx < P_C) {
            int o = off[idx] + add;
            if (idx == P_C - 1) off[P_C] = o + cur[idx];  // cur still holds count
            off[idx] = o;
            cur[idx] = o;
        }
    }
}

// ---------------------------------------------------------------------------
// scatter active entries to sorted position, 2 entries/thread, nt stores.
// ---------------------------------------------------------------------------
__global__ __launch_bounds__(256) void scat(
        const int* __restrict__ r1, const int* __restrict__ c1, const float* __restrict__ v1,
        const int* __restrict__ r2, const int* __restrict__ c2, const float* __restrict__ v2,
        const int* __restrict__ poolRk,
        int* __restrict__ cur, unsigned long long* __restrict__ suv) {
    int i2 = (blockIdx.x * 256 + threadIdx.x) * 2;
    if (i2 >= 2 * P_C) return;
    const int* rr; const int* cc; const float* vv; unsigned srcbit; int base;
    if (i2 < P_C) { rr = r1; cc = c1; vv = v1; srcbit = 0u; base = i2; }
    else          { rr = r2; cc = c2; vv = v2; srcbit = 0x100000u; base = i2 - P_C; }
    int2 r = *reinterpret_cast<const int2*>(rr + base);
    int2 c = *reinterpret_cast<const int2*>(cc + base);
    float2 v = *reinterpret_cast<const float2*>(vv + base);
    {
        int info = poolRk[r.x >> 4];
        if (info & 1) {
            int pos = atomicAdd(&cur[(info >> 1) * 16 + (r.x & 15)], 1);
            unsigned long long e = (unsigned long long)((unsigned)c.x | srcbit) |
                                   ((unsigned long long)__float_as_uint(v.x) << 32);
            __builtin_nontemporal_store(e, suv + pos);
        }
    }
    {
        int info = poolRk[r.y >> 4];
        if (info & 1) {
            int pos = atomicAdd(&cur[(info >> 1) * 16 + (r.y & 15)], 1);
            unsigned long long e = (unsigned long long)((unsigned)c.y | srcbit) |
                                   ((unsigned long long)__float_as_uint(v.y) << 32);
            __builtin_nontemporal_store(e, suv + pos);
        }
    }
}

// ---------------------------------------------------------------------------
// CSR gather: block = 4 compact rows, 16 groups of 16 lanes; each group owns
// the 4 consecutive-slot chains of one (row, slot-quad). 4 chains x 2-wide
// unrolled walk: up to 8 independent suv loads issued per iteration before
// any use — one suv round-trip + one feature round-trip per iteration
// (chains avg ~2 entries, so most groups finish in ONE iteration).
// nt loads for suv, nt stores for planes. Accumulation order per chain is
// preserved (e then e+1) — numerics identical to 1-wide walk.
// ---------------------------------------------------------------------------
#define PROC(kv, acc, isdg)  do { \
    unsigned k_ = (unsigned)(kv); float v_ = __uint_as_float((unsigned)((kv) >> 32)); \
    const float* f_ = (k_ & 0x100000u) ? efeat : x; \
    float4 fv_ = *reinterpret_cast<const float4*>(f_ + (size_t)(k_ & 0xFFFFFu) * 64 + t16 * 4); \
    acc.x = fmaf(v_, fv_.x, acc.x); acc.y = fmaf(v_, fv_.y, acc.y); \
    acc.z = fmaf(v_, fv_.z, acc.z); acc.w = fmaf(v_, fv_.w, acc.w); \
    if ((isdg) && !(k_ & 0x100000u)) dq = fmaf(v_, degs[k_ & 0xFFFFFu], dq); \
} while (0)

__global__ __launch_bounds__(256) void gather_nfeat(
        const unsigned long long* __restrict__ suv, const int* __restrict__ pOff,
        const float* __restrict__ x, const float* __restrict__ efeat,
        const float* __restrict__ degs, const int* __restrict__ nActB,
        unsigned short* __restrict__ nfH, unsigned short* __restrict__ nfL,
        float* __restrict__ degD, int row0, int rows) {
    int nAct = nActB[0];
    int t = threadIdx.x;
    int gid = t >> 4;            // 0..15  (wave = gid>>2 = row)
    int t16 = t & 15;
    int r4 = gid >> 2;           // row within block (wave-uniform)
    int q4 = gid & 3;            // slot quad
    int cr = row0 + blockIdx.x * 4 + r4;
    int rend = row0 + rows; if (rend > nAct) rend = nAct;
    if (cr >= rend) return;      // wave-uniform exit
    int sBase = cr * 16 + q4 * 4;
    int4 bo = *reinterpret_cast<const int4*>(pOff + sBase);
    int e4 = pOff[sBase + 4];
    int i0 = bo.x, e0 = bo.y;
    int i1 = bo.y, e1 = bo.z;
    int i2 = bo.z, e2 = bo.w;
    int i3 = bo.w, e3 = e4;
    float4 a0 = {0,0,0,0}, a1 = {0,0,0,0}, a2 = {0,0,0,0}, a3 = {0,0,0,0};
    float dq = 0.f;              // degree accum for sub-chain q4
    while ((i0 < e0) | (i1 < e1) | (i2 < e2) | (i3 < e3)) {
        bool h0 = i0 < e0, h1 = i1 < e1, h2 = i2 < e2, h3 = i3 < e3;
        bool g0 = i0 + 1 < e0, g1 = i1 + 1 < e1, g2 = i2 + 1 < e2, g3 = i3 + 1 < e3;
        unsigned long long ka0, kb0, ka1, kb1, ka2, kb2, ka3, kb3;
        if (h0) ka0 = __builtin_nontemporal_load(suv + i0);
        if (g0) kb0 = __builtin_nontemporal_load(suv + i0 + 1);
        if (h1) ka1 = __builtin_nontemporal_load(suv + i1);
        if (g1) kb1 = __builtin_nontemporal_load(suv + i1 + 1);
        if (h2) ka2 = __builtin_nontemporal_load(suv + i2);
        if (g2) kb2 = __builtin_nontemporal_load(suv + i2 + 1);
        if (h3) ka3 = __builtin_nontemporal_load(suv + i3);
        if (g3) kb3 = __builtin_nontemporal_load(suv + i3 + 1);
        if (h0) PROC(ka0, a0, q4 == 0);
        if (g0) PROC(kb0, a0, q4 == 0);
        if (h1) PROC(ka1, a1, q4 == 1);
        if (g1) PROC(kb1, a1, q4 == 1);
        if (h2) PROC(ka2, a2, q4 == 2);
        if (g2) PROC(kb2, a2, q4 == 2);
        if (h3) PROC(ka3, a3, q4 == 3);
        if (g3) PROC(kb3, a3, q4 == 3);
        i0 += 2; i1 += 2; i2 += 2; i3 += 2;
    }
    size_t o = ((size_t)(cr - row0) * 16 + q4 * 4) * 64 + t16 * 4;
    float4 as[4] = {a0, a1, a2, a3};
#pragma unroll
    for (int c = 0; c < 4; ++c) {
        ushort4 h4, l4;
        h4.x = f2bf(as[c].x); l4.x = f2bf(as[c].x - bf2f(h4.x));
        h4.y = f2bf(as[c].y); l4.y = f2bf(as[c].y - bf2f(h4.y));
        h4.z = f2bf(as[c].z); l4.z = f2bf(as[c].z - bf2f(h4.z));
        h4.w = f2bf(as[c].w); l4.w = f2bf(as[c].w - bf2f(h4.w));
        __builtin_nontemporal_store(pack4(h4),
            reinterpret_cast<unsigned long long*>(nfH + o + (size_t)c * 64));
        __builtin_nontemporal_store(pack4(l4),
            reinterpret_cast<unsigned long long*>(nfL + o + (size_t)c * 64));
    }
    if (t16 == 0) degD[(size_t)cr * 4 + q4] = dq;
}

// ---------------------------------------------------------------------------
// degree-gate MLP over compact rows [r0, min(r0+rows, nAct)).
// ---------------------------------------------------------------------------
__global__ __launch_bounds__(256) void dg_gemm(
        const float* __restrict__ degD,
        const float* __restrict__ W0, const float* __restrict__ b0,
        const float* __restrict__ W1, const float* __restrict__ b1,
        const int* __restrict__ nActB,
        float* __restrict__ dgb, int r0, int rows) {
    __shared__ float hidT[128][68];   // [h][r]
    __shared__ float w1T[128][68];    // [h][c]
    __shared__ float dloc[64][4];
    __shared__ float w0s[128][5];
    int nAct = nActB[0];
    int rend = r0 + rows; if (rend > nAct) rend = nAct;
    int t = threadIdx.x;
    int m0 = r0 + blockIdx.x * 64;
    if (m0 >= rend) return;

    {
        int r = t >> 2, j = t & 3;
        int gr = m0 + r; if (gr >= rend) gr = rend - 1;
        dloc[r][j] = degD[(size_t)gr * 4 + j];
    }
    if (t < 128) {
        w0s[t][0] = W0[t * 4 + 0]; w0s[t][1] = W0[t * 4 + 1];
        w0s[t][2] = W0[t * 4 + 2]; w0s[t][3] = W0[t * 4 + 3];
        w0s[t][4] = b0[t];
    }
    for (int s = 0; s < 32; ++s) {
        int idx = t + s * 256;
        w1T[idx & 127][idx >> 7] = W1[idx];
    }
    __syncthreads();
    for (int s = 0; s < 32; ++s) {
        int idx = t + s * 256;
        int h = idx & 127, r = idx >> 7;
        float v = w0s[h][4] + dloc[r][0] * w0s[h][0] + dloc[r][1] * w0s[h][1]
                            + dloc[r][2] * w0s[h][2] + dloc[r][3] * w0s[h][3];
        hidT[h][r] = fmaxf(v, 0.f);
    }
    __syncthreads();

    int tm = t >> 4, tn = t & 15;
    float acc[4][4] = {};
#pragma unroll 8
    for (int k = 0; k < 128; ++k) {
        float4 a = *reinterpret_cast<const float4*>(&hidT[k][tm * 4]);
        float4 b = *reinterpret_cast<const float4*>(&w1T[k][tn * 4]);
        acc[0][0] = fmaf(a.x, b.x, acc[0][0]); acc[0][1] = fmaf(a.x, b.y, acc[0][1]);
        acc[0][2] = fmaf(a.x, b.z, acc[0][2]); acc[0][3] = fmaf(a.x, b.w, acc[0][3]);
        acc[1][0] = fmaf(a.y, b.x, acc[1][0]); acc[1][1] = fmaf(a.y, b.y, acc[1][1]);
        acc[1][2] = fmaf(a.y, b.z, acc[1][2]); acc[1][3] = fmaf(a.y, b.w, acc[1][3]);
        acc[2][0] = fmaf(a.z, b.x, acc[2][0]); acc[2][1] = fmaf(a.z, b.y, acc[2][1]);
        acc[2][2] = fmaf(a.z, b.z, acc[2][2]); acc[2][3] = fmaf(a.z, b.w, acc[2][3]);
        acc[3][0] = fmaf(a.w, b.x, acc[3][0]); acc[3][1] = fmaf(a.w, b.y, acc[3][1]);
        acc[3][2] = fmaf(a.w, b.z, acc[3][2]); acc[3][3] = fmaf(a.w, b.w, acc[3][3]);
    }
    float bb[4] = {b1[tn * 4 + 0], b1[tn * 4 + 1], b1[tn * 4 + 2], b1[tn * 4 + 3]};
#pragma unroll
    for (int i = 0; i < 4; ++i) {
        int grow = m0 + tm * 4 + i;
        if (grow < rend) {
            float4 o = {acc[i][0] + bb[0], acc[i][1] + bb[1],
                        acc[i][2] + bb[2], acc[i][3] + bb[3]};
            *reinterpret_cast<float4*>(&dgb[(size_t)grow * 64 + tn * 4]) = o;
        }
    }
}

// ---------------------------------------------------------------------------
// MFMA einsum + epilogue (split-bf16, 3 products) over compact rows.
// ---------------------------------------------------------------------------
__global__ __launch_bounds__(256) void gemm_mfma(
        const unsigned short* __restrict__ nfH, const unsigned short* __restrict__ nfL,
        const unsigned short* __restrict__ Bpk, const unsigned short* __restrict__ Wlpk,
        const float* __restrict__ bias, const float* __restrict__ bl,
        const float* __restrict__ dgb, const int* __restrict__ nActB,
        float* __restrict__ outb, int r0, int rows) {
    __shared__ unsigned short Hh[128][72];
    __shared__ unsigned short Hl[128][72];
    int nAct = nActB[0];
    int rowsEff = rows; if (r0 + rowsEff > nAct) rowsEff = nAct - r0;
    int t = threadIdx.x, lane = t & 63, w = t >> 6;
    int m0 = blockIdx.x * 128;
    if (m0 >= rowsEff) return;
    int r16 = lane & 15, kg = lane >> 4;

    f32x4 acc[2][4];
#pragma unroll
    for (int i = 0; i < 2; ++i)
#pragma unroll
        for (int j = 0; j < 4; ++j) acc[i][j] = (f32x4){0.f, 0.f, 0.f, 0.f};

    for (int l = 0; l < 16; ++l) {
#pragma unroll
        for (int ks = 0; ks < 2; ++ks) {
            bf16x8 ah[2], al[2];
#pragma unroll
            for (int mt = 0; mt < 2; ++mt) {
                int lr = m0 + w * 32 + mt * 16 + r16;
                if (lr >= rowsEff) lr = rowsEff - 1;
                size_t off = ((size_t)lr * 16 + l) * 64 + ks * 32 + kg * 8;
                ah[mt] = *reinterpret_cast<const bf16x8*>(nfH + off);
                al[mt] = *reinterpret_cast<const bf16x8*>(nfL + off);
            }
#pragma unroll
            for (int nt = 0; nt < 4; ++nt) {
                const unsigned short* bb =
                    Bpk + (size_t)(((l * 2 + ks) * 4 + nt) * 2) * 512 + lane * 8;
                bf16x8 bh = *reinterpret_cast<const bf16x8*>(bb);
                bf16x8 blo = *reinterpret_cast<const bf16x8*>(bb + 512);
#pragma unroll
                for (int mt = 0; mt < 2; ++mt) {
                    acc[mt][nt] = __builtin_amdgcn_mfma_f32_16x16x32_bf16(ah[mt], bh,  acc[mt][nt], 0, 0, 0);
                    acc[mt][nt] = __builtin_amdgcn_mfma_f32_16x16x32_bf16(ah[mt], blo, acc[mt][nt], 0, 0, 0);
                    acc[mt][nt] = __builtin_amdgcn_mfma_f32_16x16x32_bf16(al[mt], bh,  acc[mt][nt], 0, 0, 0);
                }
            }
        }
    }

    // epilogue 1: h = relu(acc + bias) -> split-bf16 LDS planes
#pragma unroll
    for (int mt = 0; mt < 2; ++mt)
#pragma unroll
        for (int nt = 0; nt < 4; ++nt) {
            int col = nt * 16 + r16;
            float bv = bias[col];
#pragma unroll
            for (int reg = 0; reg < 4; ++reg) {
                int rl = w * 32 + mt * 16 + kg * 4 + reg;
                float h = fmaxf(acc[mt][nt][reg] + bv, 0.f);
                unsigned short hb = f2bf(h);
                Hh[rl][col] = hb;
                Hl[rl][col] = f2bf(h - bf2f(hb));
            }
        }
    __syncthreads();

    f32x4 acc2[2][4];
#pragma unroll
    for (int i = 0; i < 2; ++i)
#pragma unroll
        for (int j = 0; j < 4; ++j) acc2[i][j] = (f32x4){0.f, 0.f, 0.f, 0.f};

#pragma unroll
    for (int ks = 0; ks < 2; ++ks) {
        bf16x8 ah[2], al[2];
#pragma unroll
        for (int mt = 0; mt < 2; ++mt) {
            int rl = w * 32 + mt * 16 + r16;
            ah[mt] = *reinterpret_cast<const bf16x8*>(&Hh[rl][ks * 32 + kg * 8]);
            al[mt] = *reinterpret_cast<const bf16x8*>(&Hl[rl][ks * 32 + kg * 8]);
        }
#pragma unroll
        for (int nt = 0; nt < 4; ++nt) {
            const unsigned short* wb =
                Wlpk + (size_t)(((ks * 4 + nt) * 2)) * 512 + lane * 8;
            bf16x8 bh = *reinterpret_cast<const bf16x8*>(wb);
            bf16x8 blo = *reinterpret_cast<const bf16x8*>(wb + 512);
#pragma unroll
            for (int mt = 0; mt < 2; ++mt) {
                acc2[mt][nt] = __builtin_amdgcn_mfma_f32_16x16x32_bf16(ah[mt], bh,  acc2[mt][nt], 0, 0, 0);
                acc2[mt][nt] = __builtin_amdgcn_mfma_f32_16x16x32_bf16(ah[mt], blo, acc2[mt][nt], 0, 0, 0);
                acc2[mt][nt] = __builtin_amdgcn_mfma_f32_16x16x32_bf16(al[mt], bh,  acc2[mt][nt], 0, 0, 0);
            }
        }
    }

    // epilogue 2: out = (h2 + bl) * dg
#pragma unroll
    for (int mt = 0; mt < 2; ++mt)
#pragma unroll
        for (int nt = 0; nt < 4; ++nt) {
            int col = nt * 16 + r16;
            float bv = bl[col];
#pragma unroll
            for (int reg = 0; reg < 4; ++reg) {
                int rl = w * 32 + mt * 16 + kg * 4 + reg;
                if (m0 + rl < rowsEff) {
                    size_t idx = (size_t)(r0 + m0 + rl) * 64 + col;
                    outb[idx] = (acc2[mt][nt][reg] + bv) * dgb[idx];
                }
            }
        }
}

// ---------------------------------------------------------------------------
// pooling scatter: one 64-lane wave per nnz, 1 atomic per lane.
// ---------------------------------------------------------------------------
__global__ __launch_bounds__(256) void pool_scatter(
        const int* __restrict__ prow, const int* __restrict__ pcol,
        const float* __restrict__ pval, const int* __restrict__ poolRk,
        const float* __restrict__ outb, float* __restrict__ out) {
    int t = blockIdx.x * 256 + threadIdx.x;
    int i = t >> 6, d = t & 63;
    if (i >= NPERM_C) return;
    int r = prow[i], c = pcol[i];
    float v = pval[i];
    int cr = poolRk[c] >> 1;
    atomicAdd(&out[(size_t)r * 64 + d], v * outb[(size_t)cr * 64 + d]);
}

extern "C" void kernel_launch(void* const* d_in, const int* in_sizes, int n_in,
                              void* d_out, int out_size, void* d_ws, size_t ws_size,
                              hipStream_t stream) {
    const float* x       = (const float*)d_in[0];
    const float* efeat   = (const float*)d_in[1];
    const float* degs    = (const float*)d_in[2];
    const int*   n2p_row = (const int*)d_in[3];
    const int*   n2p_col = (const int*)d_in[4];
    const float* n2p_val = (const float*)d_in[5];
    const int*   e2p_row = (const int*)d_in[6];
    const int*   e2p_col = (const int*)d_in[7];
    const float* e2p_val = (const float*)d_in[8];
    const int*   pool_row = (const int*)d_in[9];
    const int*   pool_col = (const int*)d_in[10];
    const float* pool_val = (const float*)d_in[11];
    const float* weights = (const float*)d_in[12];
    const float* bias    = (const float*)d_in[13];
    const float* W0      = (const float*)d_in[14];
    const float* b0      = (const float*)d_in[15];
    const float* W1      = (const float*)d_in[16];
    const float* b1      = (const float*)d_in[17];
    const float* Wl      = (const float*)d_in[18];
    const float* bl      = (const float*)d_in[19];
    float* out = (float*)d_out;

    // workspace layout (4B elems)
    unsigned long long* suv = (unsigned long long*)d_ws;   // 16,000,000 (8M x 8B)
    int*   pOff     = (int*)(suv + 8000000);           //  4,000,064
    int*   pCur     = pOff + 4000064;                  //  4,000,000
    int*   bsum     = pCur + 4000000;                  //      2,048
    int*   poolCnt  = bsum + 2048;                     //    250,000
    int*   poolRk   = poolCnt + 250000;                //    250,000
    int*   bsum2    = poolRk + 250000;                 //        256
    int*   nActB    = bsum2 + 256;                     //         16
    unsigned short* Bpk  = (unsigned short*)(nActB + 16);   // 131072 us = 65536
    unsigned short* Wlpk = Bpk + 131072;                    //   8192 us =  4096
    float* degD = (float*)(Wlpk + 8192);               //  1,000,000
    float* dgb  = degD + 1000000;                      // 16,000,000
    float* outb = dgb;                                 // alias (same-idx RAW)
    unsigned short* nfH = (unsigned short*)(dgb + 16000000);

    const long long base_elems = 16000000LL + 4000064 + 4000000 + 2048 +
                                 250000 * 2 + 256 + 16 + 65536 + 4096 +
                                 1000000 + 16000000;   // 41,572,016
    long long availf = (long long)(ws_size / 4) - base_elems;
    long long chl = availf / 1024;   // per row: 2 planes * 16*64 * 2B = 4 KB
    if (chl > NPERM_C) chl = NPERM_C;
    int CH = (int)(chl & ~127LL);
    if (CH < 128) {
        hipMemsetAsync(d_out, 0, (size_t)out_size * 4, stream);
        return;
    }
    unsigned short* nfL = nfH + (size_t)CH * 1024;

    hipMemsetAsync(pCur, 0, (size_t)P_C * 4, stream);
    hipMemsetAsync(poolCnt, 0, (size_t)NPERM_C * 4, stream);
    hipMemsetAsync(out, 0, (size_t)G_C * 64 * 4, stream);

    repack_bpk<<<512, 256, 0, stream>>>(weights, Bpk);
    repack_wlpk<<<32, 256, 0, stream>>>(Wl, Wlpk);

    pool_hist<<<(NPERM_C + 255) / 256, 256, 0, stream>>>(pool_col, poolCnt);
    pool_scan_local<<<NB2, 256, 0, stream>>>(poolCnt, poolRk, bsum2);
    pool_scan_top<<<1, 256, 0, stream>>>(bsum2);
    pool_scan_add<<<NB2, 256, 0, stream>>>(poolCnt, poolRk, bsum2, nActB);

    hist<<<3907, 256, 0, stream>>>(n2p_row, e2p_row, poolRk, pCur);
    scan_local<<<NB1, 256, 0, stream>>>(pCur, pOff, bsum);
    scan_top<<<1, 256, 0, stream>>>(bsum);
    scan_add<<<NB1, 256, 0, stream>>>(pOff, bsum, pCur);
    scat<<<15625, 256, 0, stream>>>(n2p_row, n2p_col, n2p_val,
                                    e2p_row, e2p_col, e2p_val,
                                    poolRk, pCur, suv);

    for (int c0 = 0; c0 < NPERM_C; c0 += CH) {
        int rows = NPERM_C - c0; if (rows > CH) rows = CH;
        gather_nfeat<<<(rows + 3) / 4, 256, 0, stream>>>(
            suv, pOff, x, efeat, degs, nActB, nfH, nfL, degD, c0, rows);
        dg_gemm<<<(rows + 63) / 64, 256, 0, stream>>>(
            degD, W0, b0, W1, b1, nActB, dgb, c0, rows);
        gemm_mfma<<<(rows + 127) / 128, 256, 0, stream>>>(
            nfH, nfL, Bpk, Wlpk, bias, bl, dgb, nActB, outb, c0, rows);
    }

    pool_scatter<<<62500, 256, 0, stream>>>(pool_row, pool_col, pool_val,
                                            poolRk, outb, out);
}